// Round 1
// baseline (72.192 us; speedup 1.0000x reference)
//
#include <hip/hip_runtime.h>
#include <math.h>

#define NW 8

typedef float v2f __attribute__((ext_vector_type(2)));
typedef int   v2i __attribute__((ext_vector_type(2)));

__device__ __forceinline__ v2f mk2(float a, float b) { v2f r; r.x = a; r.y = b; return r; }

// ---- cross-lane exchanges: DPP for lane XOR 1/2/8, permlane32_swap for XOR 32
template<int CTRL>
__device__ __forceinline__ float dpp_x(float v) {
    return __int_as_float(
        __builtin_amdgcn_update_dpp(0, __float_as_int(v), CTRL, 0xF, 0xF, true));
}
template<int CTRL>
__device__ __forceinline__ v2f dpp2(v2f v) {
    v2f r;
    r.x = dpp_x<CTRL>(v.x);
    r.y = dpp_x<CTRL>(v.y);
    return r;
}
#define XCH1(v) dpp2<0xB1>(v)   /* quad_perm [1,0,3,2]  == lane XOR 1 */
#define XCH2(v) dpp2<0x4E>(v)   /* quad_perm [2,3,0,1]  == lane XOR 2 */
#define XCH8(v) dpp2<0x128>(v)  /* row_ror:8 on 16-rows == lane XOR 8 */

__device__ __forceinline__ float rfl(float v) {
    return __int_as_float(__builtin_amdgcn_readfirstlane(__float_as_int(v)));
}

__device__ __forceinline__ float xch32f(float v, int lane) {
#if __has_builtin(__builtin_amdgcn_permlane32_swap)
    v2i r = __builtin_amdgcn_permlane32_swap(__float_as_int(v), __float_as_int(v),
                                             false, false);
    // lanes 0..31: partner (lane+32) landed in r[1]; lanes 32..63: partner in r[0]
    return __int_as_float((lane & 32) ? r[0] : r[1]);
#else
    return __shfl_xor(v, 32, 64);
#endif
}
__device__ __forceinline__ v2f xch32_2(v2f v, int lane) {
    v2f r;
    r.x = xch32f(v.x, lane);
    r.y = xch32f(v.y, lane);
    return r;
}

// Layout: wave = 4 items. Item id g = lane bits {4,2}. Amplitude sublane
// u = lane bits {0,1,3,5} -> wires 0,1,2,3 (n bits 7,6,5,4). Each lane holds
// 16 amplitudes n = (u<<4)|j, packed as 8 float2 over j-pairs: vector index
// k = j>>1 (k bit2->wire4, bit1->wire5, bit0->wire6), j bit0 = wire7 =
// within-vector axis. Wires 0,1,2 via DPP (XOR1/XOR2/XOR8), wire3 via
// permlane32_swap (XOR32).
__global__ __launch_bounds__(256, 4) void vqc_kernel(
    const float* __restrict__ x,     // [B,8]
    const float* __restrict__ ry1,   // [8]
    const float* __restrict__ crz1,  // [8]
    const float* __restrict__ ry2,   // [8]
    const float* __restrict__ crz2,  // [8]
    float* __restrict__ out,         // [B,8]
    int B)
{
    // CRZ tables: 16 rows (one per u) x 16 floats, padded to 20 so rows stay
    // 16B-aligned (80B) and bank aliasing is <=2-way (free).
    __shared__ __align__(16) float Tc1[320], Ts1[320], Tc2[320], Ts2[320];

    const int t = threadIdx.x;
    {
        const int n = t;  // basis index 0..255
        float e1 = 0.f, e2 = 0.f;
#pragma unroll
        for (int i = 0; i < NW; ++i) {
            float bc  = (float)((n >> (7 - i)) & 1);
            float bt1 = (float)((n >> (7 - ((i + 1) & 7))) & 1);
            float bt2 = (float)((n >> (7 - ((i + 7) & 7))) & 1);
            e1 += bc * crz1[i] * (bt1 - 0.5f);
            e2 += bc * crz2[i] * (bt2 - 0.5f);
        }
        const int j = n & 15;
        const int u = n >> 4;
        const int idx = u * 20 + j;
        float s, c;
        __sincosf(e1, &s, &c);  Tc1[idx] = c;  Ts1[idx] = s;
        __sincosf(e2, &s, &c);  Tc2[idx] = c;  Ts2[idx] = s;
    }
    __syncthreads();

    const int lane = t & 63;
    // u bits: lane0->u bit3 (wire0), lane1->u bit2 (wire1), lane3->u bit1
    // (wire2), lane5->u bit0 (wire3)
    const int u = ((lane & 1) << 3) | (((lane >> 1) & 1) << 2)
                | (((lane >> 3) & 1) << 1) | ((lane >> 5) & 1);
    const int g = ((lane >> 3) & 2) | ((lane >> 2) & 1);

    // shared RY params -> SGPRs (uniform across the wave)
    float rc1[8], rs1[8], rc2[8], rs2[8];
#pragma unroll
    for (int i = 0; i < 8; ++i) {
        float s, c;
        __sincosf(0.5f * ry1[i], &s, &c);  rc1[i] = rfl(c);  rs1[i] = rfl(s);
        __sincosf(0.5f * ry2[i], &s, &c);  rc2[i] = rfl(c);  rs2[i] = rfl(s);
    }

    const float* pc1 = &Tc1[u * 20];
    const float* ps1 = &Ts1[u * 20];
    const float* pc2 = &Tc2[u * 20];
    const float* ps2 = &Ts2[u * 20];

    const int wavesPerBlock = blockDim.x >> 6;
    const int gwave = blockIdx.x * wavesPerBlock + (t >> 6);
    const int b  = gwave * 4 + g;
    const int bl = (b < B) ? b : (B - 1);

    // ---- encoding
    const float4* xp = (const float4*)(x + (size_t)bl * NW);
    float4 xa = xp[0], xb = xp[1];
    float cs[8], sn[8];
    __sincosf(0.5f * xa.x, &sn[0], &cs[0]);
    __sincosf(0.5f * xa.y, &sn[1], &cs[1]);
    __sincosf(0.5f * xa.z, &sn[2], &cs[2]);
    __sincosf(0.5f * xa.w, &sn[3], &cs[3]);
    __sincosf(0.5f * xb.x, &sn[4], &cs[4]);
    __sincosf(0.5f * xb.y, &sn[5], &cs[5]);
    __sincosf(0.5f * xb.z, &sn[6], &cs[6]);
    __sincosf(0.5f * xb.w, &sn[7], &cs[7]);

    // cross-lane factor: wire0<->lane bit0, wire1<->bit1, wire2<->bit3,
    // wire3<->bit5
    float pcf = ((lane & 1)  ? sn[0] : cs[0])
              * ((lane & 2)  ? sn[1] : cs[1])
              * ((lane & 8)  ? sn[2] : cs[2])
              * ((lane & 32) ? sn[3] : cs[3]);

    // in-lane outer product over k bits (wire4<->k bit2, wire5<->bit1,
    // wire6<->bit0), then pack wire7 via {cs7, sn7}
    float t2[2], t4[4], t8[8];
    t2[0] = pcf * cs[4];  t2[1] = pcf * sn[4];
#pragma unroll
    for (int k = 0; k < 2; ++k) { t4[2*k] = t2[k] * cs[5];  t4[2*k+1] = t2[k] * sn[5]; }
#pragma unroll
    for (int k = 0; k < 4; ++k) { t8[2*k] = t4[k] * cs[6];  t8[2*k+1] = t4[k] * sn[6]; }

    const v2f cw7 = mk2(cs[7], sn[7]);
    v2f aP[8];
#pragma unroll
    for (int k = 0; k < 8; ++k) aP[k] = mk2(t8[k], t8[k]) * cw7;

    // ---- CRZ block 1 on real state: re = a*cos, im = a*sin
    v2f reP[8], imP[8];
#pragma unroll
    for (int q = 0; q < 4; ++q) {
        float4 cq = *(const float4*)&pc1[4 * q];
        float4 sq = *(const float4*)&ps1[4 * q];
        v2f cl = mk2(cq.x, cq.y), ch = mk2(cq.z, cq.w);
        v2f sl = mk2(sq.x, sq.y), sh = mk2(sq.z, sq.w);
        reP[2*q]   = aP[2*q]   * cl;  imP[2*q]   = aP[2*q]   * sl;
        reP[2*q+1] = aP[2*q+1] * ch;  imP[2*q+1] = aP[2*q+1] * sh;
    }

#define CROSS_WIRE(RC, RS, WI, LBIT, EXCH)                                  \
    { float c_ = RC[WI], s_ = RS[WI];                                       \
      float se_ = (lane & LBIT) ? s_ : -s_;                                 \
      v2f cv = mk2(c_, c_), sev = mk2(se_, se_);                            \
      _Pragma("unroll")                                                     \
      for (int k = 0; k < 8; ++k) {                                         \
          v2f pre = EXCH(reP[k]);                                           \
          v2f pim = EXCH(imP[k]);                                           \
          reP[k] = reP[k] * cv + pre * sev;                                 \
          imP[k] = imP[k] * cv + pim * sev;                                 \
      } }

#define CROSS_WIRE32(RC, RS, WI)                                            \
    { float c_ = RC[WI], s_ = RS[WI];                                       \
      float se_ = (lane & 32) ? s_ : -s_;                                   \
      v2f cv = mk2(c_, c_), sev = mk2(se_, se_);                            \
      _Pragma("unroll")                                                     \
      for (int k = 0; k < 8; ++k) {                                         \
          v2f pre = xch32_2(reP[k], lane);                                  \
          v2f pim = xch32_2(imP[k], lane);                                  \
          reP[k] = reP[k] * cv + pre * sev;                                 \
          imP[k] = imP[k] * cv + pim * sev;                                 \
      } }

#define INLANE_WIRE(RC, RS, WI, M)                                          \
    { float c_ = RC[WI], s_ = RS[WI];                                       \
      v2f cv = mk2(c_, c_), sv = mk2(s_, s_);                               \
      _Pragma("unroll")                                                     \
      for (int k = 0; k < 8; ++k) if (!(k & M)) {                           \
          int h = k | M;                                                    \
          v2f rl = reP[k], rh = reP[h], il = imP[k], ih = imP[h];           \
          reP[k] = rl * cv - rh * sv;  reP[h] = rl * sv + rh * cv;          \
          imP[k] = il * cv - ih * sv;  imP[h] = il * sv + ih * cv;          \
      } }

#define WIRE7(RC, RS)                                                       \
    { float c_ = RC[7], s_ = RS[7];                                         \
      v2f cv = mk2(c_, c_), sev = mk2(-s_, s_);                             \
      _Pragma("unroll")                                                     \
      for (int k = 0; k < 8; ++k) {                                         \
          v2f r = reP[k], i = imP[k];                                       \
          v2f rsw = mk2(r.y, r.x), isw = mk2(i.y, i.x);                     \
          reP[k] = r * cv + rsw * sev;                                      \
          imP[k] = i * cv + isw * sev;                                      \
      } }

#define RY_LAYER(RC, RS)                                                    \
    do {                                                                    \
        CROSS_WIRE(RC, RS, 0, 1, XCH1);                                     \
        CROSS_WIRE(RC, RS, 1, 2, XCH2);                                     \
        CROSS_WIRE(RC, RS, 2, 8, XCH8);                                     \
        CROSS_WIRE32(RC, RS, 3);                                            \
        INLANE_WIRE(RC, RS, 4, 4);                                          \
        INLANE_WIRE(RC, RS, 5, 2);                                          \
        INLANE_WIRE(RC, RS, 6, 1);                                          \
        WIRE7(RC, RS);                                                      \
    } while (0)

    // ---- RY layer 1
    RY_LAYER(rc1, rs1);

    // ---- CRZ block 2: complex multiply
#pragma unroll
    for (int q = 0; q < 4; ++q) {
        float4 cq = *(const float4*)&pc2[4 * q];
        float4 sq = *(const float4*)&ps2[4 * q];
        v2f cl = mk2(cq.x, cq.y), ch = mk2(cq.z, cq.w);
        v2f sl = mk2(sq.x, sq.y), sh = mk2(sq.z, sq.w);
        v2f r, i;
        r = reP[2*q];   i = imP[2*q];
        reP[2*q]   = r * cl - i * sl;  imP[2*q]   = r * sl + i * cl;
        r = reP[2*q+1]; i = imP[2*q+1];
        reP[2*q+1] = r * ch - i * sh;  imP[2*q+1] = r * sh + i * ch;
    }

    // ---- RY layer 2
    RY_LAYER(rc2, rs2);

    // ---- probabilities (packed) + in-lane Walsh tree
    v2f pP[8];
#pragma unroll
    for (int k = 0; k < 8; ++k) pP[k] = reP[k] * reP[k] + imP[k] * imP[k];

    v2f s1v[4], dv6 = mk2(0.f, 0.f);
#pragma unroll
    for (int k = 0; k < 4; ++k) { s1v[k] = pP[2*k] + pP[2*k+1]; dv6 += pP[2*k] - pP[2*k+1]; }
    v2f s2v[2], dv5 = mk2(0.f, 0.f);
#pragma unroll
    for (int k = 0; k < 2; ++k) { s2v[k] = s1v[2*k] + s1v[2*k+1]; dv5 += s1v[2*k] - s1v[2*k+1]; }
    v2f sv0 = s2v[0] + s2v[1];
    v2f dv4 = s2v[0] - s2v[1];

    // within-vector axis is wire7
    float v0 = sv0.x + sv0.y, d7 = sv0.x - sv0.y;
    float d4 = dv4.x + dv4.y;
    float d5 = dv5.x + dv5.y, d6 = dv6.x + dv6.y;

    // ---- cross-lane Walsh butterfly on lane bits {0,1,3,5}, packed values
    v2f w1 = mk2(v0, d4), w2 = mk2(d5, d6), w3 = mk2(d7, 0.f);
#define BFLY_R(EXCH, M)                                                     \
    { v2f o1 = EXCH(w1), o2 = EXCH(w2), o3 = EXCH(w3);                      \
      if (lane & M) { w1 = o1 - w1; w2 = o2 - w2; w3 = o3 - w3; }           \
      else          { w1 = o1 + w1; w2 = o2 + w2; w3 = o3 + w3; } }
    BFLY_R(XCH1, 1);
    BFLY_R(XCH2, 2);
    BFLY_R(XCH8, 8);
    { v2f o1 = xch32_2(w1, lane), o2 = xch32_2(w2, lane), o3 = xch32_2(w3, lane);
      if (lane & 32) { w1 = o1 - w1; w2 = o2 - w2; w3 = o3 - w3; }
      else           { w1 = o1 + w1; w2 = o2 + w2; w3 = o3 + w3; } }
#undef BFLY_R

    // wire0 Walsh coeff at local lane-bits (of {0,1,3,5}) == 1; wire1 == 2;
    // wire2 == 8; wire3 == 32; plain sums (wires 4..7) at local 0.
    if (b < B) {
        const int loc = lane & 43;
        float* ob = out + (size_t)b * NW;
        if      (loc == 0)  *(float4*)(ob + 4) = make_float4(w1.y, w2.x, w2.y, w3.x);
        else if (loc == 1)  ob[0] = w1.x;
        else if (loc == 2)  ob[1] = w1.x;
        else if (loc == 8)  ob[2] = w1.x;
        else if (loc == 32) ob[3] = w1.x;
    }
#undef RY_LAYER
#undef CROSS_WIRE
#undef CROSS_WIRE32
#undef INLANE_WIRE
#undef WIRE7
}

extern "C" void kernel_launch(void* const* d_in, const int* in_sizes, int n_in,
                              void* d_out, int out_size, void* d_ws, size_t ws_size,
                              hipStream_t stream) {
    const float* x    = (const float*)d_in[0];
    const float* ry1  = (const float*)d_in[1];
    const float* crz1 = (const float*)d_in[2];
    const float* ry2  = (const float*)d_in[3];
    const float* crz2 = (const float*)d_in[4];
    float* out = (float*)d_out;

    int B = in_sizes[0] / NW;                  // 16384
    // 4 items/wave, 4 waves/block -> 16 items/block
    int blocks = (B + 15) / 16;
    if (blocks < 1) blocks = 1;
    vqc_kernel<<<blocks, 256, 0, stream>>>(x, ry1, crz1, ry2, crz2, out, B);
}

// Round 2
// 69.963 us; speedup vs baseline: 1.0319x; 1.0319x over previous
//
#include <hip/hip_runtime.h>
#include <math.h>

#define NW 8

typedef float v2f __attribute__((ext_vector_type(2)));

__device__ __forceinline__ v2f mk2(float a, float b) { v2f r; r.x = a; r.y = b; return r; }

// ---- cross-lane exchanges ---------------------------------------------------
// XOR1 / XOR2 / XOR8 on VALU via DPP; XOR4 on the DS pipe via ds_swizzle
// (BitMode xor_mask=4: offset = (4<<10)|31 = 0x101F) so it overlaps with the
// FMA stream instead of competing for VALU issue.
template<int CTRL>
__device__ __forceinline__ float dpp_x(float v) {
    return __int_as_float(
        __builtin_amdgcn_update_dpp(0, __float_as_int(v), CTRL, 0xF, 0xF, true));
}
template<int CTRL>
__device__ __forceinline__ v2f dpp2(v2f v) {
    v2f r;
    r.x = dpp_x<CTRL>(v.x);
    r.y = dpp_x<CTRL>(v.y);
    return r;
}
#define XCH1(v) dpp2<0xB1>(v)   /* quad_perm [1,0,3,2]  == lane XOR 1 */
#define XCH2(v) dpp2<0x4E>(v)   /* quad_perm [2,3,0,1]  == lane XOR 2 */
#define XCH8(v) dpp2<0x128>(v)  /* row_ror:8 on 16-rows == lane XOR 8 */

__device__ __forceinline__ float swz4f(float v) {
    return __int_as_float(__builtin_amdgcn_ds_swizzle(__float_as_int(v), 0x101F));
}
__device__ __forceinline__ v2f XCH4(v2f v) {
    v2f r;
    r.x = swz4f(v.x);
    r.y = swz4f(v.y);
    return r;
}

__device__ __forceinline__ float rfl(float v) {
    return __int_as_float(__builtin_amdgcn_readfirstlane(__float_as_int(v)));
}

// Layout: wave = 4 items. Item id g = lane bits {4,5}. Amplitude sublane
// u = lane bits {0,1,2,3} -> wires 0,1,2,3 (n bits 7,6,5,4). Each lane holds
// 16 amplitudes n = (u<<4)|j, packed as 8 float2 over j-pairs: vector index
// k = j>>1 (k bit2->wire4, bit1->wire5, bit0->wire6), j bit0 = wire7 =
// within-vector axis. Wires 0,1,3 via DPP (XOR1/XOR2/XOR8), wire2 via
// ds_swizzle (XOR4).
__global__ __launch_bounds__(256, 4) void vqc_kernel(
    const float* __restrict__ x,     // [B,8]
    const float* __restrict__ ry1,   // [8]
    const float* __restrict__ crz1,  // [8]
    const float* __restrict__ ry2,   // [8]
    const float* __restrict__ crz2,  // [8]
    float* __restrict__ out,         // [B,8]
    int B)
{
    // CRZ tables: 16 rows (one per u) x 16 floats, padded to 20 so rows stay
    // 16B-aligned (80B) and bank aliasing is <=2-way (free).
    __shared__ __align__(16) float Tc1[320], Ts1[320], Tc2[320], Ts2[320];

    const int t = threadIdx.x;
    {
        const int n = t;  // basis index 0..255
        float e1 = 0.f, e2 = 0.f;
#pragma unroll
        for (int i = 0; i < NW; ++i) {
            float bc  = (float)((n >> (7 - i)) & 1);
            float bt1 = (float)((n >> (7 - ((i + 1) & 7))) & 1);
            float bt2 = (float)((n >> (7 - ((i + 7) & 7))) & 1);
            e1 += bc * crz1[i] * (bt1 - 0.5f);
            e2 += bc * crz2[i] * (bt2 - 0.5f);
        }
        const int j = n & 15;
        const int u = n >> 4;
        const int idx = u * 20 + j;
        float s, c;
        __sincosf(e1, &s, &c);  Tc1[idx] = c;  Ts1[idx] = s;
        __sincosf(e2, &s, &c);  Tc2[idx] = c;  Ts2[idx] = s;
    }
    __syncthreads();

    const int lane = t & 63;
    // u bits: lane0->u bit3 (wire0), lane1->u bit2 (wire1), lane2->u bit1
    // (wire2), lane3->u bit0 (wire3)
    const int u = ((lane & 1) << 3) | (((lane >> 1) & 1) << 2)
                | (((lane >> 2) & 1) << 1) | ((lane >> 3) & 1);
    const int g = (lane >> 4) & 3;

    // shared RY params -> SGPRs (uniform across the wave)
    float rc1[8], rs1[8], rc2[8], rs2[8];
#pragma unroll
    for (int i = 0; i < 8; ++i) {
        float s, c;
        __sincosf(0.5f * ry1[i], &s, &c);  rc1[i] = rfl(c);  rs1[i] = rfl(s);
        __sincosf(0.5f * ry2[i], &s, &c);  rc2[i] = rfl(c);  rs2[i] = rfl(s);
    }

    const float* pc1 = &Tc1[u * 20];
    const float* ps1 = &Ts1[u * 20];
    const float* pc2 = &Tc2[u * 20];
    const float* ps2 = &Ts2[u * 20];

    const int wavesPerBlock = blockDim.x >> 6;
    const int gwave = blockIdx.x * wavesPerBlock + (t >> 6);
    const int b  = gwave * 4 + g;
    const int bl = (b < B) ? b : (B - 1);

    // ---- encoding
    const float4* xp = (const float4*)(x + (size_t)bl * NW);
    float4 xa = xp[0], xb = xp[1];
    float cs[8], sn[8];
    __sincosf(0.5f * xa.x, &sn[0], &cs[0]);
    __sincosf(0.5f * xa.y, &sn[1], &cs[1]);
    __sincosf(0.5f * xa.z, &sn[2], &cs[2]);
    __sincosf(0.5f * xa.w, &sn[3], &cs[3]);
    __sincosf(0.5f * xb.x, &sn[4], &cs[4]);
    __sincosf(0.5f * xb.y, &sn[5], &cs[5]);
    __sincosf(0.5f * xb.z, &sn[6], &cs[6]);
    __sincosf(0.5f * xb.w, &sn[7], &cs[7]);

    // cross-lane factor: wire0<->lane bit0, wire1<->bit1, wire2<->bit2,
    // wire3<->bit3
    float pcf = ((lane & 1) ? sn[0] : cs[0])
              * ((lane & 2) ? sn[1] : cs[1])
              * ((lane & 4) ? sn[2] : cs[2])
              * ((lane & 8) ? sn[3] : cs[3]);

    // in-lane outer product over k bits (wire4<->k bit2, wire5<->bit1,
    // wire6<->bit0), then pack wire7 via {cs7, sn7}
    float t2[2], t4[4], t8[8];
    t2[0] = pcf * cs[4];  t2[1] = pcf * sn[4];
#pragma unroll
    for (int k = 0; k < 2; ++k) { t4[2*k] = t2[k] * cs[5];  t4[2*k+1] = t2[k] * sn[5]; }
#pragma unroll
    for (int k = 0; k < 4; ++k) { t8[2*k] = t4[k] * cs[6];  t8[2*k+1] = t4[k] * sn[6]; }

    const v2f cw7 = mk2(cs[7], sn[7]);
    v2f aP[8];
#pragma unroll
    for (int k = 0; k < 8; ++k) aP[k] = mk2(t8[k], t8[k]) * cw7;

    // ---- CRZ block 1 on real state: re = a*cos, im = a*sin
    v2f reP[8], imP[8];
#pragma unroll
    for (int q = 0; q < 4; ++q) {
        float4 cq = *(const float4*)&pc1[4 * q];
        float4 sq = *(const float4*)&ps1[4 * q];
        v2f cl = mk2(cq.x, cq.y), ch = mk2(cq.z, cq.w);
        v2f sl = mk2(sq.x, sq.y), sh = mk2(sq.z, sq.w);
        reP[2*q]   = aP[2*q]   * cl;  imP[2*q]   = aP[2*q]   * sl;
        reP[2*q+1] = aP[2*q+1] * ch;  imP[2*q+1] = aP[2*q+1] * sh;
    }

#define CROSS_WIRE(RC, RS, WI, LBIT, EXCH)                                  \
    { float c_ = RC[WI], s_ = RS[WI];                                       \
      float se_ = (lane & LBIT) ? s_ : -s_;                                 \
      v2f cv = mk2(c_, c_), sev = mk2(se_, se_);                            \
      _Pragma("unroll")                                                     \
      for (int k = 0; k < 8; ++k) {                                         \
          v2f pre = EXCH(reP[k]);                                           \
          v2f pim = EXCH(imP[k]);                                           \
          reP[k] = reP[k] * cv + pre * sev;                                 \
          imP[k] = imP[k] * cv + pim * sev;                                 \
      } }

#define INLANE_WIRE(RC, RS, WI, M)                                          \
    { float c_ = RC[WI], s_ = RS[WI];                                       \
      v2f cv = mk2(c_, c_), sv = mk2(s_, s_);                               \
      _Pragma("unroll")                                                     \
      for (int k = 0; k < 8; ++k) if (!(k & M)) {                           \
          int h = k | M;                                                    \
          v2f rl = reP[k], rh = reP[h], il = imP[k], ih = imP[h];           \
          reP[k] = rl * cv - rh * sv;  reP[h] = rl * sv + rh * cv;          \
          imP[k] = il * cv - ih * sv;  imP[h] = il * sv + ih * cv;          \
      } }

#define WIRE7(RC, RS)                                                       \
    { float c_ = RC[7], s_ = RS[7];                                         \
      v2f cv = mk2(c_, c_), sev = mk2(-s_, s_);                             \
      _Pragma("unroll")                                                     \
      for (int k = 0; k < 8; ++k) {                                         \
          v2f r = reP[k], i = imP[k];                                       \
          v2f rsw = mk2(r.y, r.x), isw = mk2(i.y, i.x);                     \
          reP[k] = r * cv + rsw * sev;                                      \
          imP[k] = i * cv + isw * sev;                                      \
      } }

#define RY_LAYER(RC, RS)                                                    \
    do {                                                                    \
        CROSS_WIRE(RC, RS, 0, 1, XCH1);                                     \
        CROSS_WIRE(RC, RS, 1, 2, XCH2);                                     \
        CROSS_WIRE(RC, RS, 2, 4, XCH4);                                     \
        CROSS_WIRE(RC, RS, 3, 8, XCH8);                                     \
        INLANE_WIRE(RC, RS, 4, 4);                                          \
        INLANE_WIRE(RC, RS, 5, 2);                                          \
        INLANE_WIRE(RC, RS, 6, 1);                                          \
        WIRE7(RC, RS);                                                      \
    } while (0)

    // ---- RY layer 1
    RY_LAYER(rc1, rs1);

    // ---- CRZ block 2: complex multiply
#pragma unroll
    for (int q = 0; q < 4; ++q) {
        float4 cq = *(const float4*)&pc2[4 * q];
        float4 sq = *(const float4*)&ps2[4 * q];
        v2f cl = mk2(cq.x, cq.y), ch = mk2(cq.z, cq.w);
        v2f sl = mk2(sq.x, sq.y), sh = mk2(sq.z, sq.w);
        v2f r, i;
        r = reP[2*q];   i = imP[2*q];
        reP[2*q]   = r * cl - i * sl;  imP[2*q]   = r * sl + i * cl;
        r = reP[2*q+1]; i = imP[2*q+1];
        reP[2*q+1] = r * ch - i * sh;  imP[2*q+1] = r * sh + i * ch;
    }

    // ---- RY layer 2
    RY_LAYER(rc2, rs2);

    // ---- probabilities (packed) + in-lane Walsh tree
    v2f pP[8];
#pragma unroll
    for (int k = 0; k < 8; ++k) pP[k] = reP[k] * reP[k] + imP[k] * imP[k];

    v2f s1v[4], dv6 = mk2(0.f, 0.f);
#pragma unroll
    for (int k = 0; k < 4; ++k) { s1v[k] = pP[2*k] + pP[2*k+1]; dv6 += pP[2*k] - pP[2*k+1]; }
    v2f s2v[2], dv5 = mk2(0.f, 0.f);
#pragma unroll
    for (int k = 0; k < 2; ++k) { s2v[k] = s1v[2*k] + s1v[2*k+1]; dv5 += s1v[2*k] - s1v[2*k+1]; }
    v2f sv0 = s2v[0] + s2v[1];
    v2f dv4 = s2v[0] - s2v[1];

    // within-vector axis is wire7
    float v0 = sv0.x + sv0.y, d7 = sv0.x - sv0.y;
    float d4 = dv4.x + dv4.y;
    float d5 = dv5.x + dv5.y, d6 = dv6.x + dv6.y;

    // ---- cross-lane Walsh butterfly on lane bits {0,1,2,3}, packed values
    v2f w1 = mk2(v0, d4), w2 = mk2(d5, d6), w3 = mk2(d7, 0.f);
#define BFLY_R(EXCH, M)                                                     \
    { v2f o1 = EXCH(w1), o2 = EXCH(w2), o3 = EXCH(w3);                      \
      if (lane & M) { w1 = o1 - w1; w2 = o2 - w2; w3 = o3 - w3; }           \
      else          { w1 = o1 + w1; w2 = o2 + w2; w3 = o3 + w3; } }
    BFLY_R(XCH1, 1);
    BFLY_R(XCH2, 2);
    BFLY_R(XCH4, 4);
    BFLY_R(XCH8, 8);
#undef BFLY_R

    // wire0 Walsh coeff at local lane-bits (of {0,1,2,3}) == 1; wire1 == 2;
    // wire2 == 4; wire3 == 8; plain sums (wires 4..7) at local 0.
    if (b < B) {
        const int loc = lane & 15;
        float* ob = out + (size_t)b * NW;
        if      (loc == 0) *(float4*)(ob + 4) = make_float4(w1.y, w2.x, w2.y, w3.x);
        else if (loc == 1) ob[0] = w1.x;
        else if (loc == 2) ob[1] = w1.x;
        else if (loc == 4) ob[2] = w1.x;
        else if (loc == 8) ob[3] = w1.x;
    }
#undef RY_LAYER
#undef CROSS_WIRE
#undef INLANE_WIRE
#undef WIRE7
}

extern "C" void kernel_launch(void* const* d_in, const int* in_sizes, int n_in,
                              void* d_out, int out_size, void* d_ws, size_t ws_size,
                              hipStream_t stream) {
    const float* x    = (const float*)d_in[0];
    const float* ry1  = (const float*)d_in[1];
    const float* crz1 = (const float*)d_in[2];
    const float* ry2  = (const float*)d_in[3];
    const float* crz2 = (const float*)d_in[4];
    float* out = (float*)d_out;

    int B = in_sizes[0] / NW;                  // 16384
    // 4 items/wave, 4 waves/block -> 16 items/block
    int blocks = (B + 15) / 16;
    if (blocks < 1) blocks = 1;
    vqc_kernel<<<blocks, 256, 0, stream>>>(x, ry1, crz1, ry2, crz2, out, B);
}

// Round 3
// 69.606 us; speedup vs baseline: 1.0371x; 1.0051x over previous
//
#include <hip/hip_runtime.h>
#include <math.h>

#define NW 8

typedef float v2f __attribute__((ext_vector_type(2)));

__device__ __forceinline__ v2f mk2(float a, float b) { v2f r; r.x = a; r.y = b; return r; }

// ---- cross-lane exchanges: all DPP (VALU pipe, no DS) ----------------------
template<int CTRL>
__device__ __forceinline__ float dpp_x(float v) {
    return __int_as_float(
        __builtin_amdgcn_update_dpp(0, __float_as_int(v), CTRL, 0xF, 0xF, true));
}
template<int CTRL>
__device__ __forceinline__ v2f dpp2(v2f v) {
    v2f r;
    r.x = dpp_x<CTRL>(v.x);
    r.y = dpp_x<CTRL>(v.y);
    return r;
}
#define XCH1(v) dpp2<0xB1>(v)   /* quad_perm [1,0,3,2]  == lane XOR 1 */
#define XCH2(v) dpp2<0x4E>(v)   /* quad_perm [2,3,0,1]  == lane XOR 2 */
#define XCH8(v) dpp2<0x128>(v)  /* row_ror:8 on 16-rows == lane XOR 8 */

// Layout: wave = 8 items. Item id g = lane bits {5,4,2}; amplitude sublane
// u = lane bits {0,1,3}. Each lane holds 32 amplitudes n = (u0<<7)|(u1<<6)|
// (u2<<5)|j, packed as 16 float2 over j-pairs: vector index k = j>>1,
// j bit0 (wire7) = within-vector axis. k bit3->wire3 ... k bit0->wire6.
// Wires 0,1,2 cross-lane via DPP (XOR1/XOR2/XOR8 on lane bits 0,1,3).
__global__ __launch_bounds__(256, 2) void vqc_kernel(
    const float* __restrict__ x,     // [B,8]
    const float* __restrict__ ry1,   // [8]
    const float* __restrict__ crz1,  // [8]
    const float* __restrict__ ry2,   // [8]
    const float* __restrict__ crz2,  // [8]
    float* __restrict__ out,         // [B,8]
    int B)
{
    // CRZ tables: 8 rows (one per u) x 32 floats, padded to 36 so rows start
    // on disjoint bank quads; 144B rows keep 16B alignment for b128 reads.
    __shared__ __align__(16) float Tc1[288], Ts1[288], Tc2[288], Ts2[288];
    // wave-uniform RY params: [rc1(8) | rs1(8) | rc2(8) | rs2(8)]
    __shared__ __align__(16) float Rp[32];

    const int t = threadIdx.x;
    const int lane = t & 63;
    const int u = ((lane & 1) << 2) | (((lane >> 1) & 1) << 1) | ((lane >> 3) & 1);
    const int g = ((lane >> 3) & 6) | ((lane >> 2) & 1);

    const int wavesPerBlock = blockDim.x >> 6;
    const int gwave = blockIdx.x * wavesPerBlock + (t >> 6);
    const int b  = gwave * 8 + g;
    const int bl = (b < B) ? b : (B - 1);

    // ---- issue the x load first so HBM latency drains under table setup
    const float4* xp = (const float4*)(x + (size_t)bl * NW);
    float4 xa = xp[0], xb = xp[1];

    // ---- CRZ phase tables (256 threads <-> 256 basis states)
    {
        const int n = t;  // basis index 0..255
        float e1 = 0.f, e2 = 0.f;
#pragma unroll
        for (int i = 0; i < NW; ++i) {
            float bc  = (float)((n >> (7 - i)) & 1);
            float bt1 = (float)((n >> (7 - ((i + 1) & 7))) & 1);
            float bt2 = (float)((n >> (7 - ((i + 7) & 7))) & 1);
            e1 += bc * crz1[i] * (bt1 - 0.5f);
            e2 += bc * crz2[i] * (bt2 - 0.5f);
        }
        const int j = n & 31;
        const int uu = (((n >> 7) & 1) << 2) | (((n >> 6) & 1) << 1) | ((n >> 5) & 1);
        const int idx = uu * 36 + j;
        float s, c;
        __sincosf(e1, &s, &c);  Tc1[idx] = c;  Ts1[idx] = s;
        __sincosf(e2, &s, &c);  Tc2[idx] = c;  Ts2[idx] = s;
    }
    // ---- wave-uniform RY param sincos: computed once, not per lane
    if (t < 8) {
        float s, c;
        __sincosf(0.5f * ry1[t], &s, &c);  Rp[t]      = c;  Rp[8 + t]  = s;
        __sincosf(0.5f * ry2[t], &s, &c);  Rp[16 + t] = c;  Rp[24 + t] = s;
    }

    // ---- encoding (no LDS dependency: overlaps other waves' table writes)
    float cs[8], sn[8];
    __sincosf(0.5f * xa.x, &sn[0], &cs[0]);
    __sincosf(0.5f * xa.y, &sn[1], &cs[1]);
    __sincosf(0.5f * xa.z, &sn[2], &cs[2]);
    __sincosf(0.5f * xa.w, &sn[3], &cs[3]);
    __sincosf(0.5f * xb.x, &sn[4], &cs[4]);
    __sincosf(0.5f * xb.y, &sn[5], &cs[5]);
    __sincosf(0.5f * xb.z, &sn[6], &cs[6]);
    __sincosf(0.5f * xb.w, &sn[7], &cs[7]);

    // cross-lane factor: wire0<->lane bit0, wire1<->bit1, wire2<->bit3
    float pcf = ((lane & 1) ? sn[0] : cs[0])
              * ((lane & 2) ? sn[1] : cs[1])
              * ((lane & 8) ? sn[2] : cs[2]);

    // in-lane outer product over k bits (wire3<->k bit3 ... wire6<->k bit0),
    // then pack wire7 (within-vector) via {cs7, sn7}
    float t2[2], t4[4], t8[8], t16[16];
    t2[0] = pcf * cs[3];  t2[1] = pcf * sn[3];
#pragma unroll
    for (int k = 0; k < 2; ++k)  { t4[2*k]  = t2[k] * cs[4];  t4[2*k+1]  = t2[k] * sn[4]; }
#pragma unroll
    for (int k = 0; k < 4; ++k)  { t8[2*k]  = t4[k] * cs[5];  t8[2*k+1]  = t4[k] * sn[5]; }
#pragma unroll
    for (int k = 0; k < 8; ++k)  { t16[2*k] = t8[k] * cs[6];  t16[2*k+1] = t8[k] * sn[6]; }

    const v2f cw7 = mk2(cs[7], sn[7]);
    v2f aP[16];
#pragma unroll
    for (int k = 0; k < 16; ++k) aP[k] = mk2(t16[k], t16[k]) * cw7;

    __syncthreads();

    // ---- wave-uniform RY params from LDS (broadcast reads)
    float rc1[8], rs1[8], rc2[8], rs2[8];
    *(float4*)&rc1[0] = *(const float4*)&Rp[0];
    *(float4*)&rc1[4] = *(const float4*)&Rp[4];
    *(float4*)&rs1[0] = *(const float4*)&Rp[8];
    *(float4*)&rs1[4] = *(const float4*)&Rp[12];
    *(float4*)&rc2[0] = *(const float4*)&Rp[16];
    *(float4*)&rc2[4] = *(const float4*)&Rp[20];
    *(float4*)&rs2[0] = *(const float4*)&Rp[24];
    *(float4*)&rs2[4] = *(const float4*)&Rp[28];

    const float* pc1 = &Tc1[u * 36];
    const float* ps1 = &Ts1[u * 36];
    const float* pc2 = &Tc2[u * 36];
    const float* ps2 = &Ts2[u * 36];

    // ---- CRZ block 1 on real state: re = a*cos, im = a*sin
    v2f reP[16], imP[16];
#pragma unroll
    for (int q = 0; q < 8; ++q) {
        float4 cq = *(const float4*)&pc1[4 * q];
        float4 sq = *(const float4*)&ps1[4 * q];
        v2f cl = mk2(cq.x, cq.y), ch = mk2(cq.z, cq.w);
        v2f sl = mk2(sq.x, sq.y), sh = mk2(sq.z, sq.w);
        reP[2*q]   = aP[2*q]   * cl;  imP[2*q]   = aP[2*q]   * sl;
        reP[2*q+1] = aP[2*q+1] * ch;  imP[2*q+1] = aP[2*q+1] * sh;
    }

#define CROSS_WIRE(RC, RS, WI, LBIT, EXCH)                                  \
    { float c_ = RC[WI], s_ = RS[WI];                                       \
      float se_ = (lane & LBIT) ? s_ : -s_;                                 \
      v2f cv = mk2(c_, c_), sev = mk2(se_, se_);                            \
      _Pragma("unroll")                                                     \
      for (int k = 0; k < 16; ++k) {                                        \
          v2f pre = EXCH(reP[k]);                                           \
          v2f pim = EXCH(imP[k]);                                           \
          reP[k] = reP[k] * cv + pre * sev;                                 \
          imP[k] = imP[k] * cv + pim * sev;                                 \
      } }

#define INLANE_WIRE(RC, RS, WI, M)                                          \
    { float c_ = RC[WI], s_ = RS[WI];                                       \
      v2f cv = mk2(c_, c_), sv = mk2(s_, s_);                               \
      _Pragma("unroll")                                                     \
      for (int k = 0; k < 16; ++k) if (!(k & M)) {                          \
          int h = k | M;                                                    \
          v2f rl = reP[k], rh = reP[h], il = imP[k], ih = imP[h];           \
          reP[k] = rl * cv - rh * sv;  reP[h] = rl * sv + rh * cv;          \
          imP[k] = il * cv - ih * sv;  imP[h] = il * sv + ih * cv;          \
      } }

#define WIRE7(RC, RS)                                                       \
    { float c_ = RC[7], s_ = RS[7];                                         \
      v2f cv = mk2(c_, c_), sev = mk2(-s_, s_);                             \
      _Pragma("unroll")                                                     \
      for (int k = 0; k < 16; ++k) {                                        \
          v2f r = reP[k], i = imP[k];                                       \
          v2f rsw = mk2(r.y, r.x), isw = mk2(i.y, i.x);                     \
          reP[k] = r * cv + rsw * sev;                                      \
          imP[k] = i * cv + isw * sev;                                      \
      } }

#define RY_LAYER(RC, RS)                                                    \
    do {                                                                    \
        CROSS_WIRE(RC, RS, 0, 1, XCH1);                                     \
        CROSS_WIRE(RC, RS, 1, 2, XCH2);                                     \
        CROSS_WIRE(RC, RS, 2, 8, XCH8);                                     \
        INLANE_WIRE(RC, RS, 3, 8);                                          \
        INLANE_WIRE(RC, RS, 4, 4);                                          \
        INLANE_WIRE(RC, RS, 5, 2);                                          \
        INLANE_WIRE(RC, RS, 6, 1);                                          \
        WIRE7(RC, RS);                                                      \
    } while (0)

    // ---- RY layer 1
    RY_LAYER(rc1, rs1);

    // ---- CRZ block 2: complex multiply
#pragma unroll
    for (int q = 0; q < 8; ++q) {
        float4 cq = *(const float4*)&pc2[4 * q];
        float4 sq = *(const float4*)&ps2[4 * q];
        v2f cl = mk2(cq.x, cq.y), ch = mk2(cq.z, cq.w);
        v2f sl = mk2(sq.x, sq.y), sh = mk2(sq.z, sq.w);
        v2f r, i;
        r = reP[2*q];   i = imP[2*q];
        reP[2*q]   = r * cl - i * sl;  imP[2*q]   = r * sl + i * cl;
        r = reP[2*q+1]; i = imP[2*q+1];
        reP[2*q+1] = r * ch - i * sh;  imP[2*q+1] = r * sh + i * ch;
    }

    // ---- RY layer 2
    RY_LAYER(rc2, rs2);

    // ---- probabilities (packed) + in-lane Walsh tree
    v2f pP[16];
#pragma unroll
    for (int k = 0; k < 16; ++k) pP[k] = reP[k] * reP[k] + imP[k] * imP[k];

    v2f s1v[8], dv6 = mk2(0.f, 0.f);
#pragma unroll
    for (int k = 0; k < 8; ++k) { s1v[k] = pP[2*k] + pP[2*k+1]; dv6 += pP[2*k] - pP[2*k+1]; }
    v2f s2v[4], dv5 = mk2(0.f, 0.f);
#pragma unroll
    for (int k = 0; k < 4; ++k) { s2v[k] = s1v[2*k] + s1v[2*k+1]; dv5 += s1v[2*k] - s1v[2*k+1]; }
    v2f s3v[2], dv4 = mk2(0.f, 0.f);
#pragma unroll
    for (int k = 0; k < 2; ++k) { s3v[k] = s2v[2*k] + s2v[2*k+1]; dv4 += s2v[2*k] - s2v[2*k+1]; }
    v2f sv0 = s3v[0] + s3v[1];
    v2f dv3 = s3v[0] - s3v[1];

    // within-vector axis is wire7
    float v0 = sv0.x + sv0.y, d7 = sv0.x - sv0.y;
    float d3 = dv3.x + dv3.y, d4 = dv4.x + dv4.y;
    float d5 = dv5.x + dv5.y, d6 = dv6.x + dv6.y;

    // ---- cross-lane Walsh butterfly on lane bits {0,1,3}, 3 packed values
    v2f w1 = mk2(v0, d3), w2 = mk2(d4, d5), w3 = mk2(d6, d7);
#define BFLY_R(EXCH, M)                                                     \
    { v2f o1 = EXCH(w1), o2 = EXCH(w2), o3 = EXCH(w3);                      \
      if (lane & M) { w1 = o1 - w1; w2 = o2 - w2; w3 = o3 - w3; }           \
      else          { w1 = o1 + w1; w2 = o2 + w2; w3 = o3 + w3; } }
    BFLY_R(XCH1, 1);
    BFLY_R(XCH2, 2);
    BFLY_R(XCH8, 8);
#undef BFLY_R

    // wire0 Walsh coeff at local lane (bits 0,1,3) == 1; wire1 == 2;
    // wire2 == 8; plain sums (wires 3..7) at local lane 0.
    if (b < B) {
        const int loc = lane & 11;
        float* ob = out + (size_t)b * NW;
        if      (loc == 0) { ob[3] = w1.y; *(float4*)(ob + 4) = make_float4(w2.x, w2.y, w3.x, w3.y); }
        else if (loc == 1) ob[0] = w1.x;
        else if (loc == 2) ob[1] = w1.x;
        else if (loc == 8) ob[2] = w1.x;
    }
#undef RY_LAYER
#undef CROSS_WIRE
#undef INLANE_WIRE
#undef WIRE7
}

extern "C" void kernel_launch(void* const* d_in, const int* in_sizes, int n_in,
                              void* d_out, int out_size, void* d_ws, size_t ws_size,
                              hipStream_t stream) {
    const float* x    = (const float*)d_in[0];
    const float* ry1  = (const float*)d_in[1];
    const float* crz1 = (const float*)d_in[2];
    const float* ry2  = (const float*)d_in[3];
    const float* crz2 = (const float*)d_in[4];
    float* out = (float*)d_out;

    int B = in_sizes[0] / NW;                  // 16384
    // 8 items/wave, 4 waves/block -> 32 items/block
    int blocks = (B + 31) / 32;
    if (blocks < 1) blocks = 1;
    vqc_kernel<<<blocks, 256, 0, stream>>>(x, ry1, crz1, ry2, crz2, out, B);
}

// Round 4
// 69.515 us; speedup vs baseline: 1.0385x; 1.0013x over previous
//
#include <hip/hip_runtime.h>
#include <math.h>

#define NW 8

typedef float v2f __attribute__((ext_vector_type(2)));

__device__ __forceinline__ v2f mk2(float a, float b) { v2f r; r.x = a; r.y = b; return r; }

// ---- packed fp32 (VOP3P) ops: 2 lanes of f32 per instruction ---------------
__device__ __forceinline__ v2f pk_mul(v2f a, v2f b) {
    v2f d;
    asm("v_pk_mul_f32 %0, %1, %2" : "=v"(d) : "v"(a), "v"(b));
    return d;
}
__device__ __forceinline__ v2f pk_add(v2f a, v2f b) {
    v2f d;
    asm("v_pk_add_f32 %0, %1, %2" : "=v"(d) : "v"(a), "v"(b));
    return d;
}
__device__ __forceinline__ v2f pk_fma(v2f a, v2f b, v2f c) {  // a*b + c
    v2f d;
    asm("v_pk_fma_f32 %0, %1, %2, %3" : "=v"(d) : "v"(a), "v"(b), "v"(c));
    return d;
}

// ---- cross-lane exchanges: all DPP (VALU pipe, no DS) ----------------------
template<int CTRL>
__device__ __forceinline__ float dpp_x(float v) {
    return __int_as_float(
        __builtin_amdgcn_update_dpp(0, __float_as_int(v), CTRL, 0xF, 0xF, true));
}
template<int CTRL>
__device__ __forceinline__ v2f dpp2(v2f v) {
    v2f r;
    r.x = dpp_x<CTRL>(v.x);
    r.y = dpp_x<CTRL>(v.y);
    return r;
}
#define XCH1(v) dpp2<0xB1>(v)   /* quad_perm [1,0,3,2]  == lane XOR 1 */
#define XCH2(v) dpp2<0x4E>(v)   /* quad_perm [2,3,0,1]  == lane XOR 2 */
#define XCH8(v) dpp2<0x128>(v)  /* row_ror:8 on 16-rows == lane XOR 8 */

// Layout: wave = 8 items. Item id g = lane bits {5,4,2}; amplitude sublane
// u = lane bits {0,1,3}. Each lane holds 32 amplitudes n = (u0<<7)|(u1<<6)|
// (u2<<5)|j, packed as 16 float2 over j-pairs: vector index k = j>>1,
// j bit0 (wire7) = within-vector axis. k bit3->wire3 ... k bit0->wire6.
// Wires 0,1,2 cross-lane via DPP (XOR1/XOR2/XOR8 on lane bits 0,1,3).
__global__ __launch_bounds__(256, 2) void vqc_kernel(
    const float* __restrict__ x,     // [B,8]
    const float* __restrict__ ry1,   // [8]
    const float* __restrict__ crz1,  // [8]
    const float* __restrict__ ry2,   // [8]
    const float* __restrict__ crz2,  // [8]
    float* __restrict__ out,         // [B,8]
    int B)
{
    // CRZ tables: 8 rows (one per u) x 32 floats, padded to 36 so rows start
    // on disjoint bank quads; 144B rows keep 16B alignment for b128 reads.
    __shared__ __align__(16) float Tc1[288], Ts1[288], Tc2[288], Ts2[288];
    // wave-uniform RY params: [rc1(8) | rs1(8) | rc2(8) | rs2(8)]
    __shared__ __align__(16) float Rp[32];

    const int t = threadIdx.x;
    const int lane = t & 63;
    const int u = ((lane & 1) << 2) | (((lane >> 1) & 1) << 1) | ((lane >> 3) & 1);
    const int g = ((lane >> 3) & 6) | ((lane >> 2) & 1);

    const int wavesPerBlock = blockDim.x >> 6;
    const int gwave = blockIdx.x * wavesPerBlock + (t >> 6);
    const int b  = gwave * 8 + g;
    const int bl = (b < B) ? b : (B - 1);

    // ---- issue the x load first so HBM latency drains under table setup
    const float4* xp = (const float4*)(x + (size_t)bl * NW);
    float4 xa = xp[0], xb = xp[1];

    // ---- CRZ phase tables (256 threads <-> 256 basis states)
    {
        const int n = t;  // basis index 0..255
        float e1 = 0.f, e2 = 0.f;
#pragma unroll
        for (int i = 0; i < NW; ++i) {
            float bc  = (float)((n >> (7 - i)) & 1);
            float bt1 = (float)((n >> (7 - ((i + 1) & 7))) & 1);
            float bt2 = (float)((n >> (7 - ((i + 7) & 7))) & 1);
            e1 += bc * crz1[i] * (bt1 - 0.5f);
            e2 += bc * crz2[i] * (bt2 - 0.5f);
        }
        const int j = n & 31;
        const int uu = (((n >> 7) & 1) << 2) | (((n >> 6) & 1) << 1) | ((n >> 5) & 1);
        const int idx = uu * 36 + j;
        float s, c;
        __sincosf(e1, &s, &c);  Tc1[idx] = c;  Ts1[idx] = s;
        __sincosf(e2, &s, &c);  Tc2[idx] = c;  Ts2[idx] = s;
    }
    // ---- wave-uniform RY param sincos: computed once, not per lane
    if (t < 8) {
        float s, c;
        __sincosf(0.5f * ry1[t], &s, &c);  Rp[t]      = c;  Rp[8 + t]  = s;
        __sincosf(0.5f * ry2[t], &s, &c);  Rp[16 + t] = c;  Rp[24 + t] = s;
    }

    // ---- encoding (no LDS dependency: overlaps other waves' table writes)
    float cs[8], sn[8];
    __sincosf(0.5f * xa.x, &sn[0], &cs[0]);
    __sincosf(0.5f * xa.y, &sn[1], &cs[1]);
    __sincosf(0.5f * xa.z, &sn[2], &cs[2]);
    __sincosf(0.5f * xa.w, &sn[3], &cs[3]);
    __sincosf(0.5f * xb.x, &sn[4], &cs[4]);
    __sincosf(0.5f * xb.y, &sn[5], &cs[5]);
    __sincosf(0.5f * xb.z, &sn[6], &cs[6]);
    __sincosf(0.5f * xb.w, &sn[7], &cs[7]);

    // cross-lane factor: wire0<->lane bit0, wire1<->bit1, wire2<->bit3
    float pcf = ((lane & 1) ? sn[0] : cs[0])
              * ((lane & 2) ? sn[1] : cs[1])
              * ((lane & 8) ? sn[2] : cs[2]);

    // in-lane outer product over k bits (wire3<->k bit3 ... wire6<->k bit0),
    // then pack wire7 (within-vector) via {cs7, sn7}
    float t2[2], t4[4], t8[8], t16[16];
    t2[0] = pcf * cs[3];  t2[1] = pcf * sn[3];
#pragma unroll
    for (int k = 0; k < 2; ++k)  { t4[2*k]  = t2[k] * cs[4];  t4[2*k+1]  = t2[k] * sn[4]; }
#pragma unroll
    for (int k = 0; k < 4; ++k)  { t8[2*k]  = t4[k] * cs[5];  t8[2*k+1]  = t4[k] * sn[5]; }
#pragma unroll
    for (int k = 0; k < 8; ++k)  { t16[2*k] = t8[k] * cs[6];  t16[2*k+1] = t8[k] * sn[6]; }

    v2f aP[16];
#pragma unroll
    for (int k = 0; k < 16; ++k) { aP[k].x = t16[k] * cs[7]; aP[k].y = t16[k] * sn[7]; }

    __syncthreads();

    // ---- wave-uniform RY params from LDS (broadcast reads)
    float rc1[8], rs1[8], rc2[8], rs2[8];
    *(float4*)&rc1[0] = *(const float4*)&Rp[0];
    *(float4*)&rc1[4] = *(const float4*)&Rp[4];
    *(float4*)&rs1[0] = *(const float4*)&Rp[8];
    *(float4*)&rs1[4] = *(const float4*)&Rp[12];
    *(float4*)&rc2[0] = *(const float4*)&Rp[16];
    *(float4*)&rc2[4] = *(const float4*)&Rp[20];
    *(float4*)&rs2[0] = *(const float4*)&Rp[24];
    *(float4*)&rs2[4] = *(const float4*)&Rp[28];

    const float* pc1 = &Tc1[u * 36];
    const float* ps1 = &Ts1[u * 36];
    const float* pc2 = &Tc2[u * 36];
    const float* ps2 = &Ts2[u * 36];

    // ---- CRZ block 1 on real state: re = a*cos, im = a*sin  (packed)
    v2f reP[16], imP[16];
#pragma unroll
    for (int q = 0; q < 8; ++q) {
        float4 cq = *(const float4*)&pc1[4 * q];
        float4 sq = *(const float4*)&ps1[4 * q];
        v2f cl = mk2(cq.x, cq.y), ch = mk2(cq.z, cq.w);
        v2f sl = mk2(sq.x, sq.y), sh = mk2(sq.z, sq.w);
        reP[2*q]   = pk_mul(aP[2*q],   cl);  imP[2*q]   = pk_mul(aP[2*q],   sl);
        reP[2*q+1] = pk_mul(aP[2*q+1], ch);  imP[2*q+1] = pk_mul(aP[2*q+1], sh);
    }

#define CROSS_WIRE(RC, RS, WI, LBIT, EXCH)                                  \
    { float c_ = RC[WI], s_ = RS[WI];                                       \
      float se_ = (lane & LBIT) ? s_ : -s_;                                 \
      v2f cv = mk2(c_, c_), sev = mk2(se_, se_);                            \
      _Pragma("unroll")                                                     \
      for (int k = 0; k < 16; ++k) {                                        \
          v2f pre = EXCH(reP[k]);                                           \
          v2f pim = EXCH(imP[k]);                                           \
          reP[k] = pk_fma(pre, sev, pk_mul(reP[k], cv));                    \
          imP[k] = pk_fma(pim, sev, pk_mul(imP[k], cv));                    \
      } }

#define INLANE_WIRE(RC, RS, WI, M)                                          \
    { float c_ = RC[WI], s_ = RS[WI];                                       \
      v2f cv = mk2(c_, c_), sv = mk2(s_, s_), nsv = mk2(-s_, -s_);          \
      _Pragma("unroll")                                                     \
      for (int k = 0; k < 16; ++k) if (!(k & M)) {                          \
          int h = k | M;                                                    \
          v2f rl = reP[k], rh = reP[h], il = imP[k], ih = imP[h];           \
          reP[k] = pk_fma(rh, nsv, pk_mul(rl, cv));                         \
          reP[h] = pk_fma(rh, cv,  pk_mul(rl, sv));                         \
          imP[k] = pk_fma(ih, nsv, pk_mul(il, cv));                         \
          imP[h] = pk_fma(ih, cv,  pk_mul(il, sv));                         \
      } }

#define WIRE7(RC, RS)                                                       \
    { float c_ = RC[7], s_ = RS[7];                                         \
      _Pragma("unroll")                                                     \
      for (int k = 0; k < 16; ++k) {                                        \
          v2f r = reP[k], i = imP[k];                                       \
          reP[k].x = r.x * c_ - r.y * s_;  reP[k].y = r.x * s_ + r.y * c_;  \
          imP[k].x = i.x * c_ - i.y * s_;  imP[k].y = i.x * s_ + i.y * c_;  \
      } }

#define RY_LAYER(RC, RS)                                                    \
    do {                                                                    \
        CROSS_WIRE(RC, RS, 0, 1, XCH1);                                     \
        CROSS_WIRE(RC, RS, 1, 2, XCH2);                                     \
        CROSS_WIRE(RC, RS, 2, 8, XCH8);                                     \
        INLANE_WIRE(RC, RS, 3, 8);                                          \
        INLANE_WIRE(RC, RS, 4, 4);                                          \
        INLANE_WIRE(RC, RS, 5, 2);                                          \
        INLANE_WIRE(RC, RS, 6, 1);                                          \
        WIRE7(RC, RS);                                                      \
    } while (0)

    // ---- RY layer 1
    RY_LAYER(rc1, rs1);

    // ---- CRZ block 2: complex multiply (packed)
#pragma unroll
    for (int q = 0; q < 8; ++q) {
        float4 cq = *(const float4*)&pc2[4 * q];
        float4 sq = *(const float4*)&ps2[4 * q];
        v2f cl = mk2(cq.x, cq.y),  ch = mk2(cq.z, cq.w);
        v2f sl = mk2(sq.x, sq.y),  sh = mk2(sq.z, sq.w);
        v2f nsl = mk2(-sq.x, -sq.y), nsh = mk2(-sq.z, -sq.w);
        v2f r, i;
        r = reP[2*q];   i = imP[2*q];
        reP[2*q]   = pk_fma(i, nsl, pk_mul(r, cl));
        imP[2*q]   = pk_fma(i, cl,  pk_mul(r, sl));
        r = reP[2*q+1]; i = imP[2*q+1];
        reP[2*q+1] = pk_fma(i, nsh, pk_mul(r, ch));
        imP[2*q+1] = pk_fma(i, ch,  pk_mul(r, sh));
    }

    // ---- RY layer 2
    RY_LAYER(rc2, rs2);

    // ---- probabilities (packed) + in-lane Walsh tree (packed)
    const v2f neg1 = mk2(-1.f, -1.f);
    v2f pP[16];
#pragma unroll
    for (int k = 0; k < 16; ++k) pP[k] = pk_fma(imP[k], imP[k], pk_mul(reP[k], reP[k]));

    v2f s1v[8], dv6 = mk2(0.f, 0.f);
#pragma unroll
    for (int k = 0; k < 8; ++k) {
        s1v[k] = pk_add(pP[2*k], pP[2*k+1]);
        dv6 = pk_add(dv6, pk_fma(pP[2*k+1], neg1, pP[2*k]));
    }
    v2f s2v[4], dv5 = mk2(0.f, 0.f);
#pragma unroll
    for (int k = 0; k < 4; ++k) {
        s2v[k] = pk_add(s1v[2*k], s1v[2*k+1]);
        dv5 = pk_add(dv5, pk_fma(s1v[2*k+1], neg1, s1v[2*k]));
    }
    v2f s3v[2], dv4 = mk2(0.f, 0.f);
#pragma unroll
    for (int k = 0; k < 2; ++k) {
        s3v[k] = pk_add(s2v[2*k], s2v[2*k+1]);
        dv4 = pk_add(dv4, pk_fma(s2v[2*k+1], neg1, s2v[2*k]));
    }
    v2f sv0 = pk_add(s3v[0], s3v[1]);
    v2f dv3 = pk_fma(s3v[1], neg1, s3v[0]);

    // within-vector axis is wire7
    float v0 = sv0.x + sv0.y, d7 = sv0.x - sv0.y;
    float d3 = dv3.x + dv3.y, d4 = dv4.x + dv4.y;
    float d5 = dv5.x + dv5.y, d6 = dv6.x + dv6.y;

    // ---- cross-lane Walsh butterfly on lane bits {0,1,3}, 3 packed values
    // branchless: w = o + sgn*w with sgn = -1 on the high side of each bit
    v2f w1 = mk2(v0, d3), w2 = mk2(d4, d5), w3 = mk2(d6, d7);
#define BFLY_R(EXCH, M)                                                     \
    { float sg_ = (lane & M) ? -1.f : 1.f;                                  \
      v2f sg = mk2(sg_, sg_);                                               \
      v2f o1 = EXCH(w1), o2 = EXCH(w2), o3 = EXCH(w3);                      \
      w1 = pk_fma(w1, sg, o1);                                              \
      w2 = pk_fma(w2, sg, o2);                                              \
      w3 = pk_fma(w3, sg, o3); }
    BFLY_R(XCH1, 1);
    BFLY_R(XCH2, 2);
    BFLY_R(XCH8, 8);
#undef BFLY_R

    // wire0 Walsh coeff at local lane (bits 0,1,3) == 1; wire1 == 2;
    // wire2 == 8; plain sums (wires 3..7) at local lane 0.
    if (b < B) {
        const int loc = lane & 11;
        float* ob = out + (size_t)b * NW;
        if      (loc == 0) { ob[3] = w1.y; *(float4*)(ob + 4) = make_float4(w2.x, w2.y, w3.x, w3.y); }
        else if (loc == 1) ob[0] = w1.x;
        else if (loc == 2) ob[1] = w1.x;
        else if (loc == 8) ob[2] = w1.x;
    }
#undef RY_LAYER
#undef CROSS_WIRE
#undef INLANE_WIRE
#undef WIRE7
}

extern "C" void kernel_launch(void* const* d_in, const int* in_sizes, int n_in,
                              void* d_out, int out_size, void* d_ws, size_t ws_size,
                              hipStream_t stream) {
    const float* x    = (const float*)d_in[0];
    const float* ry1  = (const float*)d_in[1];
    const float* crz1 = (const float*)d_in[2];
    const float* ry2  = (const float*)d_in[3];
    const float* crz2 = (const float*)d_in[4];
    float* out = (float*)d_out;

    int B = in_sizes[0] / NW;                  // 16384
    // 8 items/wave, 4 waves/block -> 32 items/block
    int blocks = (B + 31) / 32;
    if (blocks < 1) blocks = 1;
    vqc_kernel<<<blocks, 256, 0, stream>>>(x, ry1, crz1, ry2, crz2, out, B);
}